// Round 4
// baseline (554.407 us; speedup 1.0000x reference)
//
#include <hip/hip_runtime.h>
#include <hip/hip_bf16.h>

// ---------------------------------------------------------------------------
// MultiHopGATv2, fused formulation v2.
// Per layer:
//   gemm2_bf16 : xl = X@Wl+bl AND xr = X@Wr+br in one kernel -> bf16 [N, H*C]
//   node_fused : per dst node (1 wave), online-softmax with deferred max,
//                lrelu via 0.6a+0.4|a| (abs = free VOP3 modifier),
//                ping-pong register prefetch of next edge's xl row.
// CSR over dst (storing src values directly) built once per call.
// ---------------------------------------------------------------------------

__device__ __forceinline__ float bflo(unsigned w) { return __uint_as_float(w << 16); }
__device__ __forceinline__ float bfhi(unsigned w) { return __uint_as_float(w & 0xffff0000u); }
__device__ __forceinline__ unsigned short f2bf(float v) {
    unsigned u = __float_as_uint(v);
    u = (u + 0x7fff + ((u >> 16) & 1)) >> 16;   // round-to-nearest-even
    return (unsigned short)u;
}

// ---------------- CSR build ----------------

__global__ void zero_int_k(int* p, int n) {
    int i = blockIdx.x * 256 + threadIdx.x;
    if (i < n) p[i] = 0;
}

__global__ void count_k(const int* __restrict__ dst, int* __restrict__ cnt,
                        int E, int EP) {
    int e = blockIdx.x * 256 + threadIdx.x;
    if (e >= EP) return;
    int d = (e < E) ? dst[e] : (e - E);
    atomicAdd(&cnt[d], 1);
}

__global__ void scan1_k(const int* __restrict__ cnt, int* __restrict__ offs,
                        int* __restrict__ partial, int N) {
    __shared__ int buf[2][1024];
    int g = blockIdx.x * 1024 + threadIdx.x;
    int v = (g < N) ? cnt[g] : 0;
    int pi = 0;
    buf[0][threadIdx.x] = v;
    __syncthreads();
    for (int s = 1; s < 1024; s <<= 1) {
        int t = buf[pi][threadIdx.x];
        if ((int)threadIdx.x >= s) t += buf[pi][threadIdx.x - s];
        buf[pi ^ 1][threadIdx.x] = t;
        pi ^= 1;
        __syncthreads();
    }
    int incl = buf[pi][threadIdx.x];
    if (g < N) offs[g + 1] = incl;
    if (threadIdx.x == 1023) partial[blockIdx.x] = incl;
}

__global__ void scan2_k(int* partial, int nb) {
    if (blockIdx.x == 0 && threadIdx.x == 0) {
        int run = 0;
        for (int i = 0; i < nb; i++) { int t = partial[i]; partial[i] = run; run += t; }
    }
}

__global__ void scan3_k(int* __restrict__ offs, const int* __restrict__ partial, int N) {
    int g = blockIdx.x * 1024 + threadIdx.x;
    if (g < N) offs[g + 1] += partial[blockIdx.x];
    if (g == 0) offs[0] = 0;
}

__global__ void copy_int_k(const int* __restrict__ a, int* __restrict__ b, int n) {
    int i = blockIdx.x * 256 + threadIdx.x;
    if (i < n) b[i] = a[i];
}

__global__ void fill_k(const int* __restrict__ src, const int* __restrict__ dst,
                       int* __restrict__ cursor, int* __restrict__ csrc,
                       int E, int EP) {
    int e = blockIdx.x * 256 + threadIdx.x;
    if (e >= EP) return;
    int sv, d;
    if (e < E) { sv = src[e]; d = dst[e]; }
    else       { sv = e - E;  d = sv; }
    int p = atomicAdd(&cursor[d], 1);
    csrc[p] = sv;
}

// ---------------- fused dense transform: xl AND xr in one pass ----------------
// 256 threads; thread owns CPT columns (HCT = 256*CPT) for RPT=16 rows.
template <int FIN, int CPT>
__global__ void gemm2_bf16_k(const float* __restrict__ X,
                             const float* __restrict__ Wl, const float* __restrict__ bl,
                             const float* __restrict__ Wr, const float* __restrict__ br,
                             unsigned short* __restrict__ xl, unsigned short* __restrict__ xr,
                             int N) {
    constexpr int HCT = 256 * CPT;
    constexpr int RPT = 16;
    __shared__ float Xs[RPT][FIN];
    int tid  = threadIdx.x;
    int row0 = blockIdx.x * RPT;
    for (int i = tid; i < RPT * FIN; i += 256) {
        int r = i / FIN, k = i % FIN;
        int gr = row0 + r;
        Xs[r][k] = (gr < N) ? X[(size_t)gr * FIN + k] : 0.f;
    }
    __syncthreads();
    float aL[CPT][RPT], aR[CPT][RPT];
#pragma unroll
    for (int c = 0; c < CPT; c++) {
        float b1 = bl[tid + 256 * c], b2 = br[tid + 256 * c];
#pragma unroll
        for (int r = 0; r < RPT; r++) { aL[c][r] = b1; aR[c][r] = b2; }
    }
    for (int k = 0; k < FIN; k++) {
        float wl[CPT], wr[CPT];
#pragma unroll
        for (int c = 0; c < CPT; c++) {
            wl[c] = Wl[(size_t)k * HCT + tid + 256 * c];
            wr[c] = Wr[(size_t)k * HCT + tid + 256 * c];
        }
#pragma unroll
        for (int r = 0; r < RPT; r++) {
            float xv = Xs[r][k];
#pragma unroll
            for (int c = 0; c < CPT; c++) {
                aL[c][r] = fmaf(xv, wl[c], aL[c][r]);
                aR[c][r] = fmaf(xv, wr[c], aR[c][r]);
            }
        }
    }
#pragma unroll
    for (int r = 0; r < RPT; r++) {
        int gr = row0 + r;
        if (gr < N) {
#pragma unroll
            for (int c = 0; c < CPT; c++) {
                xl[(size_t)gr * HCT + tid + 256 * c] = f2bf(aL[c][r]);
                xr[(size_t)gr * HCT + tid + 256 * c] = f2bf(aR[c][r]);
            }
        }
    }
}

// ---------------- fused node pass v2 ----------------
// One wave per dst node. Lane l owns channels [l*F, l*F+F); head = l>>4.
// lrelu(a)*att = c1*a + c2*|a| with c1=0.6*att, c2=0.4*att (abs is free).
// Deferred-max online softmax: rescale only when __any(p > m + 11).
template <int F, bool RELU>
__global__ void node_fused_k(const unsigned short* __restrict__ xl,
                             const unsigned short* __restrict__ xr,
                             const float* __restrict__ att, const float* __restrict__ bias,
                             const int* __restrict__ offs, const int* __restrict__ csrc,
                             float* __restrict__ out, int N) {
    constexpr int HCT = 64 * F;
    constexpr int NW  = F / 2;   // dwords per lane per row
    int wv   = blockIdx.x * 4 + (threadIdx.x >> 6);
    int lane = threadIdx.x & 63;
    if (wv >= N) return;

    float xrv[F], c1[F], c2[F];
    {
        const unsigned* xp = (const unsigned*)(xr + (size_t)wv * HCT + lane * F);
#pragma unroll
        for (int i = 0; i < NW; i++) {
            unsigned w = xp[i];
            xrv[2 * i] = bflo(w); xrv[2 * i + 1] = bfhi(w);
        }
#pragma unroll
        for (int i = 0; i < F; i++) {
            float a = att[lane * F + i];
            c1[i] = 0.6f * a;
            c2[i] = 0.4f * a;
        }
    }

    int o0 = offs[wv], o1 = offs[wv + 1];
    float m = -1e30f, s = 0.f;
    float acc[F];
#pragma unroll
    for (int i = 0; i < F; i++) acc[i] = 0.f;

    unsigned cur[NW], nxt[NW];
    {
        int sn = csrc[o0];
        const unsigned* xp = (const unsigned*)(xl + (size_t)sn * HCT + lane * F);
#pragma unroll
        for (int i = 0; i < NW; i++) cur[i] = xp[i];
    }

    for (int j = o0; j < o1; ++j) {
        if (j + 1 < o1) {  // wave-uniform branch: prefetch next edge's row
            int sn = csrc[j + 1];
            const unsigned* xp = (const unsigned*)(xl + (size_t)sn * HCT + lane * F);
#pragma unroll
            for (int i = 0; i < NW; i++) nxt[i] = xp[i];
        }
        float xv[F];
#pragma unroll
        for (int i = 0; i < NW; i++) {
            unsigned w = cur[i];
            xv[2 * i] = bflo(w); xv[2 * i + 1] = bfhi(w);
        }
        float p = 0.f;
#pragma unroll
        for (int i = 0; i < F; i++) {
            float a = xv[i] + xrv[i];
            p = fmaf(c1[i], a, p);
            p = fmaf(c2[i], fabsf(a), p);
        }
        p += __shfl_xor(p, 1, 64);
        p += __shfl_xor(p, 2, 64);
        p += __shfl_xor(p, 4, 64);
        p += __shfl_xor(p, 8, 64);
        if (__any(p > m + 11.f)) {           // rare: raise running max (wave-uniform)
            float nm = fmaxf(m, p);
            float r  = __expf(m - nm);
            float w  = __expf(p - nm);
            s = fmaf(s, r, w);
#pragma unroll
            for (int i = 0; i < F; i++) acc[i] = fmaf(acc[i], r, w * xv[i]);
            m = nm;
        } else {                              // common: deferred-max fast path
            float w = __expf(p - m);          // bounded by e^11
            s += w;
#pragma unroll
            for (int i = 0; i < F; i++) acc[i] = fmaf(w, xv[i], acc[i]);
        }
#pragma unroll
        for (int i = 0; i < NW; i++) cur[i] = nxt[i];
    }

    float inv = 1.f / s;
#pragma unroll
    for (int i = 0; i < F; i++) acc[i] *= inv;
#pragma unroll
    for (int i = 0; i < F; i++) {            // sum the 4 heads (lane groups of 16)
        acc[i] += __shfl_xor(acc[i], 16, 64);
        acc[i] += __shfl_xor(acc[i], 32, 64);
    }
    if (lane < 16) {
        float* op = out + (size_t)wv * (16 * F) + lane * F;
#pragma unroll
        for (int i = 0; i < F; i++) {
            float v = fmaf(acc[i], 0.25f, bias[lane * F + i]);
            if (RELU) v = fmaxf(v, 0.f);
            op[i] = v;
        }
    }
}

// ---------------------------------------------------------------------------

static inline size_t align256(size_t x) { return (x + 255) & ~(size_t)255; }

extern "C" void kernel_launch(void* const* d_in, const int* in_sizes, int n_in,
                              void* d_out, int out_size, void* d_ws, size_t ws_size,
                              hipStream_t stream) {
    const float* x  = (const float*)d_in[0];
    const int*   ei = (const int*)d_in[1];
    const int N  = in_sizes[0] / 9;
    const int E  = in_sizes[1] / 2;
    const int EP = E + N;
    const int* src = ei;
    const int* dst = ei + E;

    const float *Wl[3], *bl[3], *Wr[3], *br[3], *att[3], *bb[3];
    for (int i = 0; i < 3; i++) {
        Wl[i]  = (const float*)d_in[2 + 6 * i];
        bl[i]  = (const float*)d_in[3 + 6 * i];
        Wr[i]  = (const float*)d_in[4 + 6 * i];
        br[i]  = (const float*)d_in[5 + 6 * i];
        att[i] = (const float*)d_in[6 + 6 * i];
        bb[i]  = (const float*)d_in[7 + 6 * i];
    }

    // workspace layout (~119 MB)
    char* w = (char*)d_ws;
    unsigned short* xl = (unsigned short*)w; w += align256((size_t)N * 512 * 2);
    unsigned short* xr = (unsigned short*)w; w += align256((size_t)N * 512 * 2);
    float* hA = (float*)w;   w += align256((size_t)N * 64 * 4);
    float* hB = (float*)w;   w += align256((size_t)N * 64 * 4);
    int* offs   = (int*)w;   w += align256((size_t)(N + 1) * 4);
    int* cursor = (int*)w;   w += align256((size_t)N * 4);
    int* csrc   = (int*)w;   w += align256((size_t)EP * 4);
    int* partial = (int*)w;  w += 4096;

    // ---- CSR build over dst ----
    int* cnt = cursor;
    zero_int_k<<<(N + 255) / 256, 256, 0, stream>>>(cnt, N);
    count_k<<<(EP + 255) / 256, 256, 0, stream>>>(dst, cnt, E, EP);
    int nb = (N + 1023) / 1024;
    scan1_k<<<nb, 1024, 0, stream>>>(cnt, offs, partial, N);
    scan2_k<<<1, 64, 0, stream>>>(partial, nb);
    scan3_k<<<nb, 1024, 0, stream>>>(offs, partial, N);
    copy_int_k<<<(N + 255) / 256, 256, 0, stream>>>(offs, cursor, N);
    fill_k<<<(EP + 255) / 256, 256, 0, stream>>>(src, dst, cursor, csrc, E, EP);

    const int gemmBlocks = (N + 15) / 16;
    const int nodeBlocks = (N + 3) / 4;

    // ---- layer 0: 9 -> 64 (H*C = 256), relu ----
    gemm2_bf16_k<9, 1><<<gemmBlocks, 256, 0, stream>>>(
        x, Wl[0], bl[0], Wr[0], br[0], xl, xr, N);
    node_fused_k<4, true><<<nodeBlocks, 256, 0, stream>>>(
        xl, xr, att[0], bb[0], offs, csrc, hA, N);

    // ---- layer 1: 64 -> 64 (H*C = 256), relu ----
    gemm2_bf16_k<64, 1><<<gemmBlocks, 256, 0, stream>>>(
        hA, Wl[1], bl[1], Wr[1], br[1], xl, xr, N);
    node_fused_k<4, true><<<nodeBlocks, 256, 0, stream>>>(
        xl, xr, att[1], bb[1], offs, csrc, hB, N);

    // ---- layer 2: 64 -> 128 (H*C = 512), no relu ----
    gemm2_bf16_k<64, 2><<<gemmBlocks, 256, 0, stream>>>(
        hB, Wl[2], bl[2], Wr[2], br[2], xl, xr, N);
    node_fused_k<8, false><<<nodeBlocks, 256, 0, stream>>>(
        xl, xr, att[2], bb[2], offs, csrc, (float*)d_out, N);
}